// Round 16
// baseline (317.999 us; speedup 1.0000x reference)
//
#include <hip/hip_runtime.h>
#include <math.h>

#define BB 32
#define NN 1024
#define MM 1024
#define FF 64
#define INF_ 1e30f

typedef float f32x4 __attribute__((ext_vector_type(4)));

// ------- cost: 64x64 tile per 256-thread block; SHEARED bf16 store ------------
// costB[((row+col)&1023)*MM + row] = bf16(cost[row][col])   (64 MB total)
// Norms fused in-block from the staged LDS tiles.
__global__ __launch_bounds__(256) void cost_kernel(const float* __restrict__ x,
                                                   const float* __restrict__ y,
                                                   unsigned short* __restrict__ cost) {
    __shared__ float Xs[FF][68];   // [k][row], padded
    __shared__ float Ys[FF][68];
    __shared__ float xnl[64];
    __shared__ float ynl[64];
    const int b    = blockIdx.z;
    const int row0 = blockIdx.y * 64;
    const int col0 = blockIdx.x * 64;
    const int tid  = threadIdx.x;
    const float* xb = x + (size_t)b * NN * FF;
    const float* yb = y + (size_t)b * MM * FF;

    #pragma unroll
    for (int cc = 0; cc < 4; ++cc) {
        int s  = tid + cc * 256;      // 0..1023 float4 slots
        int r  = s >> 4;              // tile row 0..63
        int kq = s & 15;              // k-quad 0..15
        float4 vx = *(const float4*)(xb + (size_t)(row0 + r) * FF + kq * 4);
        float4 vy = *(const float4*)(yb + (size_t)(col0 + r) * FF + kq * 4);
        Xs[kq*4+0][r] = vx.x; Xs[kq*4+1][r] = vx.y; Xs[kq*4+2][r] = vx.z; Xs[kq*4+3][r] = vx.w;
        Ys[kq*4+0][r] = vy.x; Ys[kq*4+1][r] = vy.y; Ys[kq*4+2][r] = vy.z; Ys[kq*4+3][r] = vy.w;
    }
    __syncthreads();

    // fused norms: wave 0 -> xnl, wave 1 -> ynl
    if (tid < 64) {
        float s = 0.0f;
        #pragma unroll 16
        for (int k = 0; k < FF; ++k) { float v = Xs[k][tid]; s += v * v; }
        xnl[tid] = s;
    } else if (tid < 128) {
        int r = tid - 64;
        float s = 0.0f;
        #pragma unroll 16
        for (int k = 0; k < FF; ++k) { float v = Ys[k][r]; s += v * v; }
        ynl[r] = s;
    }

    const int tx = tid & 15, ty = tid >> 4;
    float acc[4][4] = {};
    #pragma unroll 16
    for (int k = 0; k < FF; ++k) {
        float4 a  = *(const float4*)&Xs[k][ty * 4];
        float4 bb = *(const float4*)&Ys[k][tx * 4];
        float av[4] = {a.x, a.y, a.z, a.w};
        float bv[4] = {bb.x, bb.y, bb.z, bb.w};
        #pragma unroll
        for (int r = 0; r < 4; ++r)
            #pragma unroll
            for (int c = 0; c < 4; ++c)
                acc[r][c] += av[r] * bv[c];
    }
    __syncthreads();   // norms visible

    unsigned short* cB = cost + (size_t)b * NN * MM;
    #pragma unroll
    for (int r = 0; r < 4; ++r) {
        int rl  = ty * 4 + r;
        int row = row0 + rl;
        float xnv = xnl[rl];
        #pragma unroll
        for (int c = 0; c < 4; ++c) {
            int cl  = tx * 4 + c;
            int col = col0 + cl;
            float v = xnv + ynl[cl] - 2.0f * acc[r][c];
            v = sqrtf(fmaxf(v, 0.0f));
            unsigned bb_ = __float_as_uint(v);
            bb_ += 0x7FFFu + ((bb_ >> 16) & 1u);          // round-to-nearest-even
            cB[(size_t)((row + col) & 1023) * MM + row] = (unsigned short)(bb_ >> 16);
        }
    }
}

// ---------------- DPP shift (gfx9 encoding, live on gfx950) -------------------
__device__ __forceinline__ float dpp_wave_shr1(float v, float oldv) {
    int t = __builtin_amdgcn_update_dpp(__float_as_int(oldv), __float_as_int(v),
                                        0x138, 0xf, 0xf, false);
    return __int_as_float(t);
}

// ---------------- bf16 row buffer (8 dwords = 16 bf16), asm-issued loads ------
struct RowBufB { f32x4 q0, q1; };

__device__ __forceinline__ void issue_rowb(RowBufB& R, const unsigned short* rowbase,
                                           unsigned voff) {
    asm volatile(
        "global_load_dwordx4 %0, %2, %3\n\t"
        "global_load_dwordx4 %1, %2, %3 offset:16"
        : "=v"(R.q0), "=v"(R.q1)
        : "v"(voff), "s"(rowbase));
}

// bf16 unpack: even elem = w<<16, odd elem = w & 0xffff0000 (pure bit-ops)
__device__ __forceinline__ void unpackb16(const RowBufB& R, float cc[16]) {
    #pragma unroll
    for (int q = 0; q < 4; ++q) {
        unsigned w0 = __float_as_uint(R.q0[q]);
        unsigned w1 = __float_as_uint(R.q1[q]);
        cc[2*q+0]   = __uint_as_float(w0 << 16);
        cc[2*q+1]   = __uint_as_float(w0 & 0xffff0000u);
        cc[8+2*q+0] = __uint_as_float(w1 << 16);
        cc[8+2*q+1] = __uint_as_float(w1 & 0xffff0000u);
    }
}

// ---------------- DTW DP over anti-diagonals: one wave per batch --------------
// lane l owns rows i in [16l, 16l+16). At diagonal d, slot i computes cell
// (i, d-i):  cur[i] = c[i] + min(prev[i], prev[i-1], prev2[i-1]).
// bf16 16-row ring: 128 ring VGPRs (same as proven fp32 8-ring), 32 requests
// in flight (<= 63 vmcnt cap), vmcnt(30)/step -> rows-ahead DOUBLES to 16,
// halving the RT/rows-ahead stall. Unpack is bit-ops only (no cvt chain).
// Compute-before-wait: min3 chain (A/B only) runs before the vmcnt.
__global__ __launch_bounds__(64)
__attribute__((amdgpu_waves_per_eu(1, 1)))
void dtw_diag_kernel(const unsigned short* __restrict__ cost, float* __restrict__ out) {
    const int b    = blockIdx.x;
    const int lane = threadIdx.x;
    const unsigned short* cbD = cost + (size_t)b * NN * MM;  // uniform
    const unsigned voff = (unsigned)lane * 32u;              // 16 bf16/lane

    RowBufB H0, H1, H2, H3, H4, H5, H6, H7, H8, H9, H10, H11, H12, H13, H14, H15;
    issue_rowb(H0,  cbD +  0 * (size_t)MM, voff);
    issue_rowb(H1,  cbD +  1 * (size_t)MM, voff);
    issue_rowb(H2,  cbD +  2 * (size_t)MM, voff);
    issue_rowb(H3,  cbD +  3 * (size_t)MM, voff);
    issue_rowb(H4,  cbD +  4 * (size_t)MM, voff);
    issue_rowb(H5,  cbD +  5 * (size_t)MM, voff);
    issue_rowb(H6,  cbD +  6 * (size_t)MM, voff);
    issue_rowb(H7,  cbD +  7 * (size_t)MM, voff);
    issue_rowb(H8,  cbD +  8 * (size_t)MM, voff);
    issue_rowb(H9,  cbD +  9 * (size_t)MM, voff);
    issue_rowb(H10, cbD + 10 * (size_t)MM, voff);
    issue_rowb(H11, cbD + 11 * (size_t)MM, voff);
    issue_rowb(H12, cbD + 12 * (size_t)MM, voff);
    issue_rowb(H13, cbD + 13 * (size_t)MM, voff);
    issue_rowb(H14, cbD + 14 * (size_t)MM, voff);
    issue_rowb(H15, cbD + 15 * (size_t)MM, voff);

    float A[16], B[16];
    #pragma unroll
    for (int j = 0; j < 16; ++j) { A[j] = INF_; B[j] = INF_; }
    float bnd = 0.0f;    // diag-neighbor injected at (0,0) only; INF_ afterwards

    // one diagonal: min3 chain first (A/B only), THEN wait oldest row,
    // bit-unpack + add, then reissue (NR always a valid row)
    #define DIAG_STEP(Hk, PV, P2, NR)                                          \
    {                                                                          \
        float pvm1 = dpp_wave_shr1(PV[15], INF_);                              \
        float p2m1 = dpp_wave_shr1(P2[15], bnd);                               \
        float t[16];                                                           \
        _Pragma("unroll")                                                      \
        for (int r = 0; r < 16; ++r) {                                         \
            float pv_r = PV[r], p2_r = P2[r];                                  \
            t[r] = fminf(fminf(pv_r, pvm1), p2m1);                             \
            pvm1 = pv_r; p2m1 = p2_r;                                          \
        }                                                                      \
        asm volatile("s_waitcnt vmcnt(30)" ::: "memory");                      \
        __builtin_amdgcn_sched_barrier(0);                                     \
        float cc[16]; unpackb16(Hk, cc);                                       \
        _Pragma("unroll")                                                      \
        for (int r = 0; r < 16; ++r) P2[r] = cc[r] + t[r];                     \
        __builtin_amdgcn_sched_barrier(0);                                     \
        issue_rowb(Hk, cbD + (size_t)(NR) * MM, voff);                         \
    }

    // peel first 16 diagonals (d = 0..15); bnd -> INF_ after d = 0
    DIAG_STEP(H0,  A, B, 16)   bnd = INF_;
    DIAG_STEP(H1,  B, A, 17)
    DIAG_STEP(H2,  A, B, 18)
    DIAG_STEP(H3,  B, A, 19)
    DIAG_STEP(H4,  A, B, 20)
    DIAG_STEP(H5,  B, A, 21)
    DIAG_STEP(H6,  A, B, 22)
    DIAG_STEP(H7,  B, A, 23)
    DIAG_STEP(H8,  A, B, 24)
    DIAG_STEP(H9,  B, A, 25)
    DIAG_STEP(H10, A, B, 26)
    DIAG_STEP(H11, B, A, 27)
    DIAG_STEP(H12, A, B, 28)
    DIAG_STEP(H13, B, A, 29)
    DIAG_STEP(H14, A, B, 30)
    DIAG_STEP(H15, B, A, 31)

    // main: d0 = 16..2016 step 16 (126 blocks -> diags 16..2031)
    for (int d0 = 16; d0 < 2032; d0 += 16) {
        DIAG_STEP(H0,  A, B, ((d0 + 16) & 1023))
        DIAG_STEP(H1,  B, A, ((d0 + 17) & 1023))
        DIAG_STEP(H2,  A, B, ((d0 + 18) & 1023))
        DIAG_STEP(H3,  B, A, ((d0 + 19) & 1023))
        DIAG_STEP(H4,  A, B, ((d0 + 20) & 1023))
        DIAG_STEP(H5,  B, A, ((d0 + 21) & 1023))
        DIAG_STEP(H6,  A, B, ((d0 + 22) & 1023))
        DIAG_STEP(H7,  B, A, ((d0 + 23) & 1023))
        DIAG_STEP(H8,  A, B, ((d0 + 24) & 1023))
        DIAG_STEP(H9,  B, A, ((d0 + 25) & 1023))
        DIAG_STEP(H10, A, B, ((d0 + 26) & 1023))
        DIAG_STEP(H11, B, A, ((d0 + 27) & 1023))
        DIAG_STEP(H12, A, B, ((d0 + 28) & 1023))
        DIAG_STEP(H13, B, A, ((d0 + 29) & 1023))
        DIAG_STEP(H14, A, B, ((d0 + 30) & 1023))
        DIAG_STEP(H15, B, A, ((d0 + 31) & 1023))
    }

    // tail: d = 2032..2046 (15 steps; dummy reissues keep vmcnt invariant)
    DIAG_STEP(H0,  A, B, 0)
    DIAG_STEP(H1,  B, A, 1)
    DIAG_STEP(H2,  A, B, 2)
    DIAG_STEP(H3,  B, A, 3)
    DIAG_STEP(H4,  A, B, 4)
    DIAG_STEP(H5,  B, A, 5)
    DIAG_STEP(H6,  A, B, 6)
    DIAG_STEP(H7,  B, A, 7)
    DIAG_STEP(H8,  A, B, 8)
    DIAG_STEP(H9,  B, A, 9)
    DIAG_STEP(H10, A, B, 10)
    DIAG_STEP(H11, B, A, 11)
    DIAG_STEP(H12, A, B, 12)
    DIAG_STEP(H13, B, A, 13)
    DIAG_STEP(H14, A, B, 14)   // d = 2046 writes B; D(1023,1023) = B[15]@lane63
    #undef DIAG_STEP

    if (lane == 63) out[b] = B[15];
}

// ---------------- fused fallback (no workspace): cost on the fly --------------
__global__ __launch_bounds__(1024) void dtw_fused_kernel(const float* __restrict__ x,
                                                         const float* __restrict__ y,
                                                         float* __restrict__ out) {
    const int b    = blockIdx.x;
    const int tid  = threadIdx.x;
    const int lane = tid & 63;
    const int wid  = tid >> 6;
    __shared__ float P[MM];
    __shared__ float xrow[FF];
    __shared__ float part_sum[16];
    __shared__ float part_min[16];

    float yr[FF];
    const float* yrow = y + ((size_t)b * MM + tid) * FF;
    #pragma unroll
    for (int q = 0; q < FF / 4; ++q) {
        float4 v = ((const float4*)yrow)[q];
        yr[q*4+0] = v.x; yr[q*4+1] = v.y; yr[q*4+2] = v.z; yr[q*4+3] = v.w;
    }

    P[tid] = INF_;
    __syncthreads();

    const float* xb = x + (size_t)b * NN * FF;
    float result = 0.0f;

    for (int i = 0; i < NN; ++i) {
        if (tid < FF) xrow[tid] = xb[(size_t)i * FF + tid];
        float up   = P[tid];
        float diag = (tid == 0) ? (i == 0 ? 0.0f : INF_) : P[tid - 1];
        float m    = fminf(up, diag);
        __syncthreads();

        float ss = 0.0f;
        #pragma unroll 16
        for (int k = 0; k < FF; ++k) {
            float d = xrow[k] - yr[k];
            ss += d * d;
        }
        float c = sqrtf(ss);

        float s = c;
        #pragma unroll
        for (int d = 1; d < 64; d <<= 1) {
            float t = __shfl_up(s, d, 64);
            if (lane >= d) s += t;
        }
        if (lane == 63) part_sum[wid] = s;
        __syncthreads();
        if (tid < 16) {
            float p = part_sum[tid];
            #pragma unroll
            for (int d = 1; d < 16; d <<= 1) {
                float t = __shfl_up(p, d, 64);
                if (tid >= d) p += t;
            }
            part_sum[tid] = p;
        }
        __syncthreads();
        float C = s + (wid > 0 ? part_sum[wid - 1] : 0.0f);

        float z = c + m - C;
        float w = z;
        #pragma unroll
        for (int d = 1; d < 64; d <<= 1) {
            float t = __shfl_up(w, d, 64);
            if (lane >= d) w = fminf(w, t);
        }
        if (lane == 63) part_min[wid] = w;
        __syncthreads();
        if (tid < 16) {
            float p = part_min[tid];
            #pragma unroll
            for (int d = 1; d < 16; d <<= 1) {
                float t = __shfl_up(p, d, 64);
                if (tid >= d) p = fminf(p, t);
            }
            part_min[tid] = p;
        }
        __syncthreads();
        float wm  = (wid > 0) ? fminf(w, part_min[wid - 1]) : w;
        float cur = C + wm;

        P[tid] = cur;
        __syncthreads();
        if (i == NN - 1 && tid == MM - 1) result = cur;
    }
    if (tid == MM - 1) out[b] = result;
}

extern "C" void kernel_launch(void* const* d_in, const int* in_sizes, int n_in,
                              void* d_out, int out_size, void* d_ws, size_t ws_size,
                              hipStream_t stream) {
    const float* x = (const float*)d_in[0];
    const float* y = (const float*)d_in[1];
    float* out = (float*)d_out;

    size_t need = (size_t)BB * NN * MM * sizeof(unsigned short);

    if (ws_size >= need) {
        unsigned short* cost = (unsigned short*)d_ws;
        hipLaunchKernelGGL(cost_kernel, dim3(MM / 64, NN / 64, BB), dim3(256), 0, stream,
                           x, y, cost);
        hipLaunchKernelGGL(dtw_diag_kernel, dim3(BB), dim3(64), 0, stream, cost, out);
    } else {
        hipLaunchKernelGGL(dtw_fused_kernel, dim3(BB), dim3(1024), 0, stream, x, y, out);
    }
}